// Round 9
// baseline (157.849 us; speedup 1.0000x reference)
//
#include <hip/hip_runtime.h>
#include <hip/hip_bf16.h>
#include <math.h>

#define B_ROWS 4096
#define D_DIM 512
#define TWO_B 8192
#define HW_N 256
#define BASE_T 0.07f
#define ALPHA_C 0.5f
#define LOG2E 1.44269504088896340736f

typedef float v4f __attribute__((ext_vector_type(4)));

__device__ __forceinline__ float fast_exp2(float x) {
#if __has_builtin(__builtin_amdgcn_exp2f)
    return __builtin_amdgcn_exp2f(x);
#else
    return exp2f(x);
#endif
}

// ---------------------------------------------------------------------------
// Kernel 1: normalize, temps, pos_sim; write X as packed fp8 e4m3 (OCP).
// ---------------------------------------------------------------------------
__global__ __launch_bounds__(256) void prep_kernel(
    const float* __restrict__ emb1, const float* __restrict__ emb2,
    const float* __restrict__ att, unsigned short* __restrict__ X8,
    float* __restrict__ inv_temp, float* __restrict__ pos)
{
    const int b = blockIdx.x;
    const int t = threadIdx.x;
    const float2 a1 = ((const float2*)(emb1 + (size_t)b * D_DIM))[t];
    const float2 a2 = ((const float2*)(emb2 + (size_t)b * D_DIM))[t];
    float av = att[(size_t)b * HW_N + t];
    float s1  = a1.x * a1.x + a1.y * a1.y;
    float s2  = a2.x * a2.x + a2.y * a2.y;
    float s12 = a1.x * a2.x + a1.y * a2.y;
    #pragma unroll
    for (int m = 1; m < 64; m <<= 1) {
        s1  += __shfl_xor(s1, m, 64);
        s2  += __shfl_xor(s2, m, 64);
        s12 += __shfl_xor(s12, m, 64);
        av  += __shfl_xor(av, m, 64);
    }
    __shared__ float red[4][4];
    const int w = t >> 6, lane = t & 63;
    if (lane == 0) { red[w][0] = s1; red[w][1] = s2; red[w][2] = s12; red[w][3] = av; }
    __syncthreads();
    const float T1  = red[0][0] + red[1][0] + red[2][0] + red[3][0];
    const float T2  = red[0][1] + red[1][1] + red[2][1] + red[3][1];
    const float T12 = red[0][2] + red[1][2] + red[2][2] + red[3][2];
    const float Ta  = red[0][3] + red[1][3] + red[2][3] + red[3][3];
    const float i1 = 1.0f / fmaxf(sqrtf(T1), 1e-12f);
    const float i2 = 1.0f / fmaxf(sqrtf(T2), 1e-12f);
    const float it = 1.0f / (BASE_T * (1.0f + ALPHA_C * (Ta * (1.0f / 256.0f))));
    const int p1 = __builtin_amdgcn_cvt_pk_fp8_f32(a1.x * i1, a1.y * i1, 0, false);
    const int p2 = __builtin_amdgcn_cvt_pk_fp8_f32(a2.x * i2, a2.y * i2, 0, false);
    X8[(size_t)b * 256 + t]            = (unsigned short)(p1 & 0xffff);
    X8[(size_t)(b + B_ROWS) * 256 + t] = (unsigned short)(p2 & 0xffff);
    if (t == 0) {
        inv_temp[b] = it * LOG2E;
        inv_temp[b + B_ROWS] = it * LOG2E;
        pos[b] = (T12 * i1 * i2) * it;       // ln units, exact fp32
    }
}

// ---------------------------------------------------------------------------
// Kernel 2: triangular Gram (rb<=cb), FP8 e4m3. 128 KB DYNAMIC LDS
// (residency 1): two BK=256 phase buffers, phase-1 glds issued BEFORE
// phase-0 compute (glds has no dest register -> compiler cannot sink it,
// unlike R7's VGPR prefetch). Drains: phase-0 fill exposed once; phase-1
// drain at 2nd barrier lands ~2k cyc after issue -> hidden. No LDS reuse.
// ---------------------------------------------------------------------------
__device__ __forceinline__ void gload_lds16(const void* g, void* s) {
    __builtin_amdgcn_global_load_lds(
        (const __attribute__((address_space(1))) unsigned int*)g,
        (__attribute__((address_space(3))) unsigned int*)s,
        16, 0, 0);
}

__global__ __launch_bounds__(256) void gram_kernel(
    const unsigned char* __restrict__ X8,
    const float* __restrict__ inv_temp,
    float* __restrict__ partial)
{
    extern __shared__ unsigned char sm[];
    // layout: [0,32K) A-phase0 | [32K,64K) A-phase1 | [64K,96K) B-ph0 | [96K,128K) B-ph1
    const int bid = (blockIdx.x & 7) * 260 + (blockIdx.x >> 3);
    int rb = (int)((129.0f - sqrtf(129.0f * 129.0f - 8.0f * (float)bid)) * 0.5f);
    rb = rb < 0 ? 0 : (rb > 63 ? 63 : rb);
    while (rb > 0 && (rb * (129 - rb)) / 2 > bid) rb--;
    while (rb < 63 && ((rb + 1) * (129 - (rb + 1))) / 2 <= bid) rb++;
    const int cb = rb + (bid - (rb * (129 - rb)) / 2);

    const int rowBase = rb * 128;
    const int colBase = cb * 128;

    const int tid  = threadIdx.x;
    const int w    = tid >> 6;
    const int lane = tid & 63;
    const int quad = lane >> 4;
    const int t    = lane & 15;
    const int wm   = w >> 1;
    const int wn   = w & 1;

    const int srow   = lane >> 4;   // 0..3
    const int schunk = lane & 15;   // 0..15

    const unsigned char* Arow0 = X8 + (size_t)rowBase * D_DIM;
    const unsigned char* Brow0 = X8 + (size_t)colBase * D_DIM;

    v4f acc[4][4];
    #pragma unroll
    for (int a = 0; a < 4; a++)
        #pragma unroll
        for (int b2 = 0; b2 < 4; b2++)
            acc[a][b2] = v4f{0.0f, 0.0f, 0.0f, 0.0f};

    // ---- stage phase 0 (k bytes [0,256)) ----
    #pragma unroll
    for (int j = 0; j < 8; j++) {
        const int g = w * 8 + j;            // row group (4 rows), wave-uniform
        const int r = g * 4 + srow;
        const int gc = schunk ^ (r & 15);
        gload_lds16(Arow0 + (size_t)r * D_DIM + gc * 16, &sm[g * 1024]);
        gload_lds16(Brow0 + (size_t)r * D_DIM + gc * 16, &sm[65536 + g * 1024]);
    }
    __syncthreads();   // pipeline fill: exposed once

    // ---- issue phase-1 staging BEFORE phase-0 compute (fire-and-forget) ----
    #pragma unroll
    for (int j = 0; j < 8; j++) {
        const int g = w * 8 + j;
        const int r = g * 4 + srow;
        const int gc = schunk ^ (r & 15);
        gload_lds16(Arow0 + (size_t)r * D_DIM + 256 + gc * 16, &sm[32768 + g * 1024]);
        gload_lds16(Brow0 + (size_t)r * D_DIM + 256 + gc * 16, &sm[98304 + g * 1024]);
    }

    #pragma unroll
    for (int p = 0; p < 2; p++) {
        const unsigned char* bA = sm + p * 32768;
        const unsigned char* bB = sm + 65536 + p * 32768;
        #pragma unroll
        for (int s = 0; s < 8; s++) {
            const int pu = (s * 2 + (quad >> 1)) ^ t;   // XOR-swizzled 16B unit
            const int off = pu * 16 + (quad & 1) * 8;
            long aF[4], bF[4];
            #pragma unroll
            for (int mi = 0; mi < 4; mi++)
                aF[mi] = *(const long*)&bA[(wm * 64 + mi * 16 + t) * 256 + off];
            #pragma unroll
            for (int ni = 0; ni < 4; ni++)
                bF[ni] = *(const long*)&bB[(wn * 64 + ni * 16 + t) * 256 + off];
            #pragma unroll
            for (int mi = 0; mi < 4; mi++)
                #pragma unroll
                for (int ni = 0; ni < 4; ni++)
                    acc[mi][ni] = __builtin_amdgcn_mfma_f32_16x16x32_fp8_fp8(
                        aF[mi], bF[ni], acc[mi][ni], 0, 0, 0);
        }
        if (p == 0) __syncthreads();   // drains phase-1 glds issued ~2k cyc ago
    }

    // ---- Epilogue 1: row sums (temp_i), slice 2*cb+wn ----
    v4f itv[4];
    #pragma unroll
    for (int mi = 0; mi < 4; mi++)
        itv[mi] = *(const v4f*)&inv_temp[rowBase + wm * 64 + mi * 16 + quad * 4];

    float* prow = partial + (size_t)(cb * 2 + wn) * TWO_B;
    #pragma unroll
    for (int mi = 0; mi < 4; mi++) {
        #pragma unroll
        for (int r = 0; r < 4; r++) {
            const int i = rowBase + wm * 64 + mi * 16 + quad * 4 + r;
            const float it = itv[mi][r];
            float s = 0.0f;
            #pragma unroll
            for (int ni = 0; ni < 4; ni++) {
                const int j = colBase + wn * 64 + ni * 16 + t;
                const float v = fast_exp2(acc[mi][ni][r] * it);
                s += (i == j) ? 0.0f : v;
            }
            s += __shfl_xor(s, 1, 64);
            s += __shfl_xor(s, 2, 64);
            s += __shfl_xor(s, 4, 64);
            s += __shfl_xor(s, 8, 64);
            if (t == 0) prow[i] = s;
        }
    }

    // ---- Epilogue 2 (off-diag): col sums (temp_j), slice 2*rb+wm ----
    if (rb != cb) {
        float itj[4];
        float cs[4] = {0.0f, 0.0f, 0.0f, 0.0f};
        #pragma unroll
        for (int ni = 0; ni < 4; ni++)
            itj[ni] = inv_temp[colBase + wn * 64 + ni * 16 + t];
        #pragma unroll
        for (int mi = 0; mi < 4; mi++)
            #pragma unroll
            for (int r = 0; r < 4; r++)
                #pragma unroll
                for (int ni = 0; ni < 4; ni++)
                    cs[ni] += fast_exp2(acc[mi][ni][r] * itj[ni]);
        float* pcol = partial + (size_t)(rb * 2 + wm) * TWO_B;
        #pragma unroll
        for (int ni = 0; ni < 4; ni++) {
            cs[ni] += __shfl_xor(cs[ni], 16, 64);
            cs[ni] += __shfl_xor(cs[ni], 32, 64);
            if (quad == 0) pcol[colBase + wn * 64 + ni * 16 + t] = cs[ni];
        }
    }
}

// ---------------------------------------------------------------------------
// Kernel 3a/3b: reduce
// ---------------------------------------------------------------------------
__global__ __launch_bounds__(256) void finish1(
    const float* __restrict__ partial, const float* __restrict__ pos,
    float* __restrict__ blockSums)
{
    const int i = blockIdx.x * 256 + threadIdx.x;
    float d = 0.0f;
    #pragma unroll 8
    for (int s = 0; s < 128; s++) d += partial[(size_t)s * TWO_B + i];
    float li = logf(d) - pos[i & (B_ROWS - 1)];
    #pragma unroll
    for (int m = 1; m < 64; m <<= 1) li += __shfl_xor(li, m, 64);
    __shared__ float red[4];
    const int w = threadIdx.x >> 6, lane = threadIdx.x & 63;
    if (lane == 0) red[w] = li;
    __syncthreads();
    if (threadIdx.x == 0) blockSums[blockIdx.x] = red[0] + red[1] + red[2] + red[3];
}

__global__ void finish2(const float* __restrict__ blockSums, float* __restrict__ out)
{
    const int lane = threadIdx.x;
    float v = (lane < 32) ? blockSums[lane] : 0.0f;
    #pragma unroll
    for (int m = 1; m < 64; m <<= 1) v += __shfl_xor(v, m, 64);
    if (lane == 0) out[0] = v * (1.0f / 8192.0f);
}

// ---------------------------------------------------------------------------
extern "C" void kernel_launch(void* const* d_in, const int* in_sizes, int n_in,
                              void* d_out, int out_size, void* d_ws, size_t ws_size,
                              hipStream_t stream) {
    const float* emb1 = (const float*)d_in[0];
    const float* emb2 = (const float*)d_in[1];
    const float* att  = (const float*)d_in[2];
    float* out = (float*)d_out;

    char* ws = (char*)d_ws;
    unsigned short* X8 = (unsigned short*)ws;
    float* inv_temp    = (float*)(ws + 4194304);
    float* pos         = (float*)(ws + 4194304 + 32768);
    float* partial     = (float*)(ws + 4194304 + 32768 + 16384);
    float* blockSums   = (float*)(ws + 4194304 + 32768 + 16384 + 4194304);

    static bool attr_set = false;  // host-side only; same work every call
    if (!attr_set) {
        hipFuncSetAttribute((const void*)gram_kernel,
                            hipFuncAttributeMaxDynamicSharedMemorySize, 131072);
        attr_set = true;
    }

    prep_kernel<<<B_ROWS, 256, 0, stream>>>(emb1, emb2, att, X8, inv_temp, pos);
    gram_kernel<<<2080, 256, 131072, stream>>>((const unsigned char*)X8, inv_temp, partial);
    finish1<<<TWO_B / 256, 256, 0, stream>>>(partial, pos, blockSums);
    finish2<<<1, 64, 0, stream>>>(blockSums, out);
}

// Round 10
// 156.340 us; speedup vs baseline: 1.0097x; 1.0097x over previous
//
#include <hip/hip_runtime.h>
#include <hip/hip_bf16.h>
#include <math.h>

#define B_ROWS 4096
#define D_DIM 512
#define TWO_B 8192
#define HW_N 256
#define BASE_T 0.07f
#define ALPHA_C 0.5f
#define LOG2E 1.44269504088896340736f

typedef float v4f __attribute__((ext_vector_type(4)));

__device__ __forceinline__ float fast_exp2(float x) {
#if __has_builtin(__builtin_amdgcn_exp2f)
    return __builtin_amdgcn_exp2f(x);
#else
    return exp2f(x);
#endif
}

// ---------------------------------------------------------------------------
// Kernel 1: normalize, temps, pos_sim; write X as packed fp8 e4m3 (OCP).
// ---------------------------------------------------------------------------
__global__ __launch_bounds__(256) void prep_kernel(
    const float* __restrict__ emb1, const float* __restrict__ emb2,
    const float* __restrict__ att, unsigned short* __restrict__ X8,
    float* __restrict__ inv_temp, float* __restrict__ pos)
{
    const int b = blockIdx.x;
    const int t = threadIdx.x;
    const float2 a1 = ((const float2*)(emb1 + (size_t)b * D_DIM))[t];
    const float2 a2 = ((const float2*)(emb2 + (size_t)b * D_DIM))[t];
    float av = att[(size_t)b * HW_N + t];
    float s1  = a1.x * a1.x + a1.y * a1.y;
    float s2  = a2.x * a2.x + a2.y * a2.y;
    float s12 = a1.x * a2.x + a1.y * a2.y;
    #pragma unroll
    for (int m = 1; m < 64; m <<= 1) {
        s1  += __shfl_xor(s1, m, 64);
        s2  += __shfl_xor(s2, m, 64);
        s12 += __shfl_xor(s12, m, 64);
        av  += __shfl_xor(av, m, 64);
    }
    __shared__ float red[4][4];
    const int w = t >> 6, lane = t & 63;
    if (lane == 0) { red[w][0] = s1; red[w][1] = s2; red[w][2] = s12; red[w][3] = av; }
    __syncthreads();
    const float T1  = red[0][0] + red[1][0] + red[2][0] + red[3][0];
    const float T2  = red[0][1] + red[1][1] + red[2][1] + red[3][1];
    const float T12 = red[0][2] + red[1][2] + red[2][2] + red[3][2];
    const float Ta  = red[0][3] + red[1][3] + red[2][3] + red[3][3];
    const float i1 = 1.0f / fmaxf(sqrtf(T1), 1e-12f);
    const float i2 = 1.0f / fmaxf(sqrtf(T2), 1e-12f);
    const float it = 1.0f / (BASE_T * (1.0f + ALPHA_C * (Ta * (1.0f / 256.0f))));
    const int p1 = __builtin_amdgcn_cvt_pk_fp8_f32(a1.x * i1, a1.y * i1, 0, false);
    const int p2 = __builtin_amdgcn_cvt_pk_fp8_f32(a2.x * i2, a2.y * i2, 0, false);
    X8[(size_t)b * 256 + t]            = (unsigned short)(p1 & 0xffff);
    X8[(size_t)(b + B_ROWS) * 256 + t] = (unsigned short)(p2 & 0xffff);
    if (t == 0) {
        inv_temp[b] = it * LOG2E;
        inv_temp[b + B_ROWS] = it * LOG2E;
        pos[b] = (T12 * i1 * i2) * it;       // ln units, exact fp32
    }
}

// ---------------------------------------------------------------------------
// Kernel 2: 256x256 group-tile Gram over 32x32 triangular group grid
// (h<=g, 528 blocks). 512 threads = 8 waves (2/SIMD ALWAYS - R9 lesson),
// each wave 64x128 (acc[4][8]). FP8 e4m3. BK=128, double-buffered 128KB
// dynamic LDS; next phase's glds issued before compute (un-sinkable) so
// only the first fill drain is exposed. Diagonal group-blocks compute the
// full square (row sums only, diag masked); off-diag add col sums.
// ---------------------------------------------------------------------------
__device__ __forceinline__ void gload_lds16(const void* g, void* s) {
    __builtin_amdgcn_global_load_lds(
        (const __attribute__((address_space(1))) unsigned int*)g,
        (__attribute__((address_space(3))) unsigned int*)s,
        16, 0, 0);
}

__global__ __launch_bounds__(512, 2) void gram_kernel(
    const unsigned char* __restrict__ X8,
    const float* __restrict__ inv_temp,
    float* __restrict__ partialR,   // [64][8192]  row-sum slices (2g+wn)
    float* __restrict__ partialC)   // [128][8192] col-sum slices (4h+wm)
{
    extern __shared__ unsigned char sm[];
    // [0,32K) A-buf0 | [32K,64K) B-buf0 | [64K,96K) A-buf1 | [96K,128K) B-buf1

    // --- XCD-contiguous remap: 528 = 8 x 66 ---
    const int raw = blockIdx.x;
    const int bid = (raw & 7) * 66 + (raw >> 3);
    // --- triangular over 32 groups: f(h) = h*(65-h)/2 ---
    int h = (int)((65.0f - sqrtf(65.0f * 65.0f - 8.0f * (float)bid)) * 0.5f);
    h = h < 0 ? 0 : (h > 31 ? 31 : h);
    while (h > 0 && (h * (65 - h)) / 2 > bid) h--;
    while (h < 31 && ((h + 1) * (64 - h)) / 2 <= bid) h++;
    const int g = h + (bid - (h * (65 - h)) / 2);

    const int rowBase = h * 256;
    const int colBase = g * 256;

    const int tid  = threadIdx.x;
    const int w    = tid >> 6;      // 0..7
    const int lane = tid & 63;
    const int quad = lane >> 4;
    const int t    = lane & 15;
    const int wm   = w >> 1;        // 0..3 (row quarter)
    const int wn   = w & 1;         // 0..1 (col half)

    // staging roles: each glds = 8 rows x 8 units(16B) = 1 KB
    const int srow = lane >> 3;     // 0..7
    const int sc   = lane & 7;      // 0..7
    const int gcx  = sc ^ srow;     // XOR swizzle via global address

    const unsigned char* Arow0 = X8 + (size_t)rowBase * D_DIM;
    const unsigned char* Brow0 = X8 + (size_t)colBase * D_DIM;

    unsigned char* const bA0 = sm;
    unsigned char* const bB0 = sm + 32768;
    unsigned char* const bA1 = sm + 65536;
    unsigned char* const bB1 = sm + 98304;

    v4f acc[4][8];
    #pragma unroll
    for (int a = 0; a < 4; a++)
        #pragma unroll
        for (int b2 = 0; b2 < 8; b2++)
            acc[a][b2] = v4f{0.0f, 0.0f, 0.0f, 0.0f};

#define STAGE(PH, BA, BB)                                                     \
    {                                                                         \
        const int kk = (PH) * 128;                                            \
        _Pragma("unroll")                                                     \
        for (int j = 0; j < 4; j++) {                                         \
            const int ga = w * 4 + j;          /* 0..31, wave-uniform */      \
            const int r = ga * 8 + srow;       /* 0..255 */                   \
            gload_lds16(Arow0 + (size_t)r * D_DIM + kk + gcx * 16,            \
                        (BA) + ga * 1024);                                    \
            gload_lds16(Brow0 + (size_t)r * D_DIM + kk + gcx * 16,            \
                        (BB) + ga * 1024);                                    \
        }                                                                     \
    }

#define COMPUTE(BA, BB)                                                       \
    {                                                                         \
        _Pragma("unroll")                                                     \
        for (int s = 0; s < 4; s++) {                                         \
            const int u = s * 2 + (quad >> 1);                                \
            const int half = (quad & 1) * 8;                                  \
            long aF[4], bF[8];                                                \
            _Pragma("unroll")                                                 \
            for (int mi = 0; mi < 4; mi++) {                                  \
                const int row = wm * 64 + mi * 16 + t;                        \
                const int pu = u ^ (row & 7);                                 \
                aF[mi] = *(const long*)&(BA)[row * 128 + pu * 16 + half];     \
            }                                                                 \
            _Pragma("unroll")                                                 \
            for (int ni = 0; ni < 8; ni++) {                                  \
                const int col = wn * 128 + ni * 16 + t;                       \
                const int pu = u ^ (col & 7);                                 \
                bF[ni] = *(const long*)&(BB)[col * 128 + pu * 16 + half];     \
            }                                                                 \
            _Pragma("unroll")                                                 \
            for (int mi = 0; mi < 4; mi++)                                    \
                _Pragma("unroll")                                             \
                for (int ni = 0; ni < 8; ni++)                                \
                    acc[mi][ni] = __builtin_amdgcn_mfma_f32_16x16x32_fp8_fp8( \
                        aF[mi], bF[ni], acc[mi][ni], 0, 0, 0);                \
        }                                                                     \
    }

    STAGE(0, bA0, bB0)
    __syncthreads();          // pipeline fill: exposed once
    STAGE(1, bA1, bB1)        // fire-and-forget, drains at next barrier
    COMPUTE(bA0, bB0)
    __syncthreads();          // buf1 ready (issued ~2k cyc ago); buf0 free
    STAGE(2, bA0, bB0)
    COMPUTE(bA1, bB1)
    __syncthreads();
    STAGE(3, bA1, bB1)
    COMPUTE(bA0, bB0)
    __syncthreads();
    COMPUTE(bA1, bB1)

#undef STAGE
#undef COMPUTE

    // ---- Epilogue 1 (all blocks): row sums with temp_i -> pR[2g+wn] ----
    v4f itv[4];
    #pragma unroll
    for (int mi = 0; mi < 4; mi++)
        itv[mi] = *(const v4f*)&inv_temp[rowBase + wm * 64 + mi * 16 + quad * 4];

    float* pR = partialR + (size_t)(g * 2 + wn) * TWO_B;
    #pragma unroll
    for (int mi = 0; mi < 4; mi++) {
        #pragma unroll
        for (int r = 0; r < 4; r++) {
            const int i = rowBase + wm * 64 + mi * 16 + quad * 4 + r;
            const float it = itv[mi][r];
            float s = 0.0f;
            #pragma unroll
            for (int ni = 0; ni < 8; ni++) {
                const int j = colBase + wn * 128 + ni * 16 + t;
                const float v = fast_exp2(acc[mi][ni][r] * it);
                s += (i == j) ? 0.0f : v;
            }
            s += __shfl_xor(s, 1, 64);
            s += __shfl_xor(s, 2, 64);
            s += __shfl_xor(s, 4, 64);
            s += __shfl_xor(s, 8, 64);
            if (t == 0) pR[i] = s;
        }
    }

    // ---- Epilogue 2 (h<g): col sums with temp_j -> pC[4h+wm] ----
    if (h != g) {
        float* pC = partialC + (size_t)(h * 4 + wm) * TWO_B;
        #pragma unroll
        for (int ni = 0; ni < 8; ni++) {
            const int j = colBase + wn * 128 + ni * 16 + t;
            const float itj = inv_temp[j];
            float cs = 0.0f;
            #pragma unroll
            for (int mi = 0; mi < 4; mi++)
                #pragma unroll
                for (int r = 0; r < 4; r++)
                    cs += fast_exp2(acc[mi][ni][r] * itj);
            cs += __shfl_xor(cs, 16, 64);
            cs += __shfl_xor(cs, 32, 64);
            if (quad == 0) pC[j] = cs;
        }
    }
}

// ---------------------------------------------------------------------------
// Kernel 3a: denom from valid partial ranges; loss_i; block sums.
// Row i (group gi): pR[c][i] valid for c >= 2*gi; pC[s][i] valid for s < 4*gi.
// ---------------------------------------------------------------------------
__global__ __launch_bounds__(256) void finish1(
    const float* __restrict__ partialR, const float* __restrict__ partialC,
    const float* __restrict__ pos, float* __restrict__ blockSums)
{
    const int i = blockIdx.x * 256 + threadIdx.x;
    const int gi = i >> 8;
    float d = 0.0f;
    for (int c = 2 * gi; c < 64; c++) d += partialR[(size_t)c * TWO_B + i];
    const int smax = 4 * gi;
    for (int s = 0; s < smax; s++) d += partialC[(size_t)s * TWO_B + i];
    float li = logf(d) - pos[i & (B_ROWS - 1)];
    #pragma unroll
    for (int m = 1; m < 64; m <<= 1) li += __shfl_xor(li, m, 64);
    __shared__ float red[4];
    const int w = threadIdx.x >> 6, lane = threadIdx.x & 63;
    if (lane == 0) red[w] = li;
    __syncthreads();
    if (threadIdx.x == 0) blockSums[blockIdx.x] = red[0] + red[1] + red[2] + red[3];
}

__global__ void finish2(const float* __restrict__ blockSums, float* __restrict__ out)
{
    const int lane = threadIdx.x;
    float v = (lane < 32) ? blockSums[lane] : 0.0f;
    #pragma unroll
    for (int m = 1; m < 64; m <<= 1) v += __shfl_xor(v, m, 64);
    if (lane == 0) out[0] = v * (1.0f / 8192.0f);
}

// ---------------------------------------------------------------------------
extern "C" void kernel_launch(void* const* d_in, const int* in_sizes, int n_in,
                              void* d_out, int out_size, void* d_ws, size_t ws_size,
                              hipStream_t stream) {
    const float* emb1 = (const float*)d_in[0];
    const float* emb2 = (const float*)d_in[1];
    const float* att  = (const float*)d_in[2];
    float* out = (float*)d_out;

    char* ws = (char*)d_ws;
    // X8 fp8 [8192*512]          @ 0         (4 MB)
    // inv_temp f32 [8192]        @ 4194304   (32 KB)
    // pos f32 [4096]             @ 4227072   (16 KB)
    // partialR f32 [64*8192]     @ 4243456   (2 MB)
    // partialC f32 [128*8192]    @ 6340608   (4 MB)
    // blockSums f32 [32]         @ 10534912
    unsigned short* X8 = (unsigned short*)ws;
    float* inv_temp    = (float*)(ws + 4194304);
    float* pos         = (float*)(ws + 4227072);
    float* partialR    = (float*)(ws + 4243456);
    float* partialC    = (float*)(ws + 6340608);
    float* blockSums   = (float*)(ws + 10534912);

    static bool attr_set = false;  // host-side only; same device work every call
    if (!attr_set) {
        hipFuncSetAttribute((const void*)gram_kernel,
                            hipFuncAttributeMaxDynamicSharedMemorySize, 131072);
        attr_set = true;
    }

    prep_kernel<<<B_ROWS, 256, 0, stream>>>(emb1, emb2, att, X8, inv_temp, pos);
    gram_kernel<<<528, 512, 131072, stream>>>((const unsigned char*)X8,
                                              inv_temp, partialR, partialC);
    finish1<<<TWO_B / 256, 256, 0, stream>>>(partialR, partialC, pos, blockSums);
    finish2<<<1, 64, 0, stream>>>(blockSums, out);
}

// Round 11
// 142.767 us; speedup vs baseline: 1.1056x; 1.0951x over previous
//
#include <hip/hip_runtime.h>
#include <hip/hip_bf16.h>
#include <math.h>

#define B_ROWS 4096
#define D_DIM 512
#define TWO_B 8192
#define HW_N 256
#define BASE_T 0.07f
#define ALPHA_C 0.5f
#define LOG2E 1.44269504088896340736f

// padded LDS group: 4 rows x 256 B = 1024 B data + 32 B pad
#define GSTRIDE 1056
#define ABUF (32 * GSTRIDE)       // 33792 B per matrix

typedef float v4f __attribute__((ext_vector_type(4)));

__device__ __forceinline__ float fast_exp2(float x) {
#if __has_builtin(__builtin_amdgcn_exp2f)
    return __builtin_amdgcn_exp2f(x);
#else
    return exp2f(x);
#endif
}

// ---------------------------------------------------------------------------
// Kernel 1: normalize, temps, pos_sim; write X as packed fp8 e4m3 (OCP).
// ---------------------------------------------------------------------------
__global__ __launch_bounds__(256) void prep_kernel(
    const float* __restrict__ emb1, const float* __restrict__ emb2,
    const float* __restrict__ att, unsigned short* __restrict__ X8,
    float* __restrict__ inv_temp, float* __restrict__ pos)
{
    const int b = blockIdx.x;
    const int t = threadIdx.x;
    const float2 a1 = ((const float2*)(emb1 + (size_t)b * D_DIM))[t];
    const float2 a2 = ((const float2*)(emb2 + (size_t)b * D_DIM))[t];
    float av = att[(size_t)b * HW_N + t];
    float s1  = a1.x * a1.x + a1.y * a1.y;
    float s2  = a2.x * a2.x + a2.y * a2.y;
    float s12 = a1.x * a2.x + a1.y * a2.y;
    #pragma unroll
    for (int m = 1; m < 64; m <<= 1) {
        s1  += __shfl_xor(s1, m, 64);
        s2  += __shfl_xor(s2, m, 64);
        s12 += __shfl_xor(s12, m, 64);
        av  += __shfl_xor(av, m, 64);
    }
    __shared__ float red[4][4];
    const int w = t >> 6, lane = t & 63;
    if (lane == 0) { red[w][0] = s1; red[w][1] = s2; red[w][2] = s12; red[w][3] = av; }
    __syncthreads();
    const float T1  = red[0][0] + red[1][0] + red[2][0] + red[3][0];
    const float T2  = red[0][1] + red[1][1] + red[2][1] + red[3][1];
    const float T12 = red[0][2] + red[1][2] + red[2][2] + red[3][2];
    const float Ta  = red[0][3] + red[1][3] + red[2][3] + red[3][3];
    const float i1 = 1.0f / fmaxf(sqrtf(T1), 1e-12f);
    const float i2 = 1.0f / fmaxf(sqrtf(T2), 1e-12f);
    const float it = 1.0f / (BASE_T * (1.0f + ALPHA_C * (Ta * (1.0f / 256.0f))));
    const int p1 = __builtin_amdgcn_cvt_pk_fp8_f32(a1.x * i1, a1.y * i1, 0, false);
    const int p2 = __builtin_amdgcn_cvt_pk_fp8_f32(a2.x * i2, a2.y * i2, 0, false);
    X8[(size_t)b * 256 + t]            = (unsigned short)(p1 & 0xffff);
    X8[(size_t)(b + B_ROWS) * 256 + t] = (unsigned short)(p2 & 0xffff);
    if (t == 0) {
        inv_temp[b] = it * LOG2E;
        inv_temp[b + B_ROWS] = it * LOG2E;
        pos[b] = (T12 * i1 * i2) * it;       // ln units, exact fp32
    }
}

// ---------------------------------------------------------------------------
// Kernel 2: triangular Gram (rb<=cb), FP8 e4m3, R8 structure with ONE change:
// glds global addresses are LANE-LINEAR (no XOR on the global side — theory:
// the XOR permutation defeated glds coalescing, ~6x delivery loss). Bank
// conflicts handled instead by padding each 4-row glds group to 1056 B:
// fragment-read bank = 8*(t>>2) + 8*s + 2*quad (all 16 combos distinct
// mod 32) -> structural-minimum b64 LDS access. 2 phases BK=256,
// 67584 B dynamic LDS x2 blocks/CU. Fused exp row/col sums unchanged.
// ---------------------------------------------------------------------------
__device__ __forceinline__ void gload_lds16(const void* g, void* s) {
    __builtin_amdgcn_global_load_lds(
        (const __attribute__((address_space(1))) unsigned int*)g,
        (__attribute__((address_space(3))) unsigned int*)s,
        16, 0, 0);
}

__global__ __launch_bounds__(256) void gram_kernel(
    const unsigned char* __restrict__ X8,
    const float* __restrict__ inv_temp,
    float* __restrict__ partial)
{
    extern __shared__ unsigned char sm[];   // [0,ABUF) A | [ABUF,2*ABUF) B

    // --- XCD-contiguous remap: 2080 = 8 XCDs x 260 contiguous tri-ids ---
    const int bid = (blockIdx.x & 7) * 260 + (blockIdx.x >> 3);
    int rb = (int)((129.0f - sqrtf(129.0f * 129.0f - 8.0f * (float)bid)) * 0.5f);
    rb = rb < 0 ? 0 : (rb > 63 ? 63 : rb);
    while (rb > 0 && (rb * (129 - rb)) / 2 > bid) rb--;
    while (rb < 63 && ((rb + 1) * (129 - (rb + 1))) / 2 <= bid) rb++;
    const int cb = rb + (bid - (rb * (129 - rb)) / 2);

    const int rowBase = rb * 128;
    const int colBase = cb * 128;

    const int tid  = threadIdx.x;
    const int w    = tid >> 6;
    const int lane = tid & 63;
    const int quad = lane >> 4;
    const int t    = lane & 15;
    const int wm   = w >> 1;
    const int wn   = w & 1;

    // staging roles: each glds covers 4 rows x 16 chunks(16B) = 1 KB,
    // LANE-LINEAR global: lane -> row (lane>>4), chunk (lane&15)
    const int srow   = lane >> 4;   // 0..3
    const int schunk = lane & 15;   // 0..15

    const unsigned char* Arow0 = X8 + (size_t)rowBase * D_DIM;
    const unsigned char* Brow0 = X8 + (size_t)colBase * D_DIM;

    v4f acc[4][4];
    #pragma unroll
    for (int a = 0; a < 4; a++)
        #pragma unroll
        for (int b2 = 0; b2 < 4; b2++)
            acc[a][b2] = v4f{0.0f, 0.0f, 0.0f, 0.0f};

    // fragment LDS offsets (row = base+t -> group base+(t>>2), sub t&3)
    int aOff[4], bOff[4];
    #pragma unroll
    for (int mi = 0; mi < 4; mi++)
        aOff[mi] = (wm * 16 + mi * 4 + (t >> 2)) * GSTRIDE + (t & 3) * 256;
    #pragma unroll
    for (int ni = 0; ni < 4; ni++)
        bOff[ni] = ABUF + (wn * 16 + ni * 4 + (t >> 2)) * GSTRIDE + (t & 3) * 256;

    for (int p = 0; p < 2; p++) {
        const int kk = p * 256;     // byte offset into each 512 B row
        #pragma unroll
        for (int j = 0; j < 8; j++) {
            const int g = w * 8 + j;            // row group 0..31 (4 rows)
            const int r = g * 4 + srow;
            gload_lds16(Arow0 + (size_t)r * D_DIM + kk + schunk * 16,
                        &sm[g * GSTRIDE]);
            gload_lds16(Brow0 + (size_t)r * D_DIM + kk + schunk * 16,
                        &sm[ABUF + g * GSTRIDE]);
        }
        __syncthreads();

        #pragma unroll
        for (int s = 0; s < 8; s++) {
            const int off = s * 32 + quad * 8;   // linear k mapping, no XOR
            long aF[4], bF[4];
            #pragma unroll
            for (int mi = 0; mi < 4; mi++)
                aF[mi] = *(const long*)&sm[aOff[mi] + off];
            #pragma unroll
            for (int ni = 0; ni < 4; ni++)
                bF[ni] = *(const long*)&sm[bOff[ni] + off];
            #pragma unroll
            for (int mi = 0; mi < 4; mi++)
                #pragma unroll
                for (int ni = 0; ni < 4; ni++)
                    acc[mi][ni] = __builtin_amdgcn_mfma_f32_16x16x32_fp8_fp8(
                        aF[mi], bF[ni], acc[mi][ni], 0, 0, 0);
        }
        if (p == 0) __syncthreads();   // protect LDS before phase-1 overwrite
    }

    // ---- Epilogue 1: row sums (temp_i), slice 2*cb+wn ----
    v4f itv[4];
    #pragma unroll
    for (int mi = 0; mi < 4; mi++)
        itv[mi] = *(const v4f*)&inv_temp[rowBase + wm * 64 + mi * 16 + quad * 4];

    float* prow = partial + (size_t)(cb * 2 + wn) * TWO_B;
    #pragma unroll
    for (int mi = 0; mi < 4; mi++) {
        #pragma unroll
        for (int r = 0; r < 4; r++) {
            const int i = rowBase + wm * 64 + mi * 16 + quad * 4 + r;
            const float it = itv[mi][r];
            float s = 0.0f;
            #pragma unroll
            for (int ni = 0; ni < 4; ni++) {
                const int j = colBase + wn * 64 + ni * 16 + t;
                const float v = fast_exp2(acc[mi][ni][r] * it);
                s += (i == j) ? 0.0f : v;
            }
            s += __shfl_xor(s, 1, 64);
            s += __shfl_xor(s, 2, 64);
            s += __shfl_xor(s, 4, 64);
            s += __shfl_xor(s, 8, 64);
            if (t == 0) prow[i] = s;
        }
    }

    // ---- Epilogue 2 (off-diag): col sums (temp_j), slice 2*rb+wm ----
    if (rb != cb) {
        float itj[4];
        float cs[4] = {0.0f, 0.0f, 0.0f, 0.0f};
        #pragma unroll
        for (int ni = 0; ni < 4; ni++)
            itj[ni] = inv_temp[colBase + wn * 64 + ni * 16 + t];
        #pragma unroll
        for (int mi = 0; mi < 4; mi++)
            #pragma unroll
            for (int r = 0; r < 4; r++)
                #pragma unroll
                for (int ni = 0; ni < 4; ni++)
                    cs[ni] += fast_exp2(acc[mi][ni][r] * itj[ni]);
        float* pcol = partial + (size_t)(rb * 2 + wm) * TWO_B;
        #pragma unroll
        for (int ni = 0; ni < 4; ni++) {
            cs[ni] += __shfl_xor(cs[ni], 16, 64);
            cs[ni] += __shfl_xor(cs[ni], 32, 64);
            if (quad == 0) pcol[colBase + wn * 64 + ni * 16 + t] = cs[ni];
        }
    }
}

// ---------------------------------------------------------------------------
// Kernel 3a: denom = sum of 128 slices; loss_i = log(denom) - pos; block sums
// (R8 version: fixed trip count, unrolled)
// ---------------------------------------------------------------------------
__global__ __launch_bounds__(256) void finish1(
    const float* __restrict__ partial, const float* __restrict__ pos,
    float* __restrict__ blockSums)
{
    const int i = blockIdx.x * 256 + threadIdx.x;
    float d = 0.0f;
    #pragma unroll 8
    for (int s = 0; s < 128; s++) d += partial[(size_t)s * TWO_B + i];
    float li = logf(d) - pos[i & (B_ROWS - 1)];
    #pragma unroll
    for (int m = 1; m < 64; m <<= 1) li += __shfl_xor(li, m, 64);
    __shared__ float red[4];
    const int w = threadIdx.x >> 6, lane = threadIdx.x & 63;
    if (lane == 0) red[w] = li;
    __syncthreads();
    if (threadIdx.x == 0) blockSums[blockIdx.x] = red[0] + red[1] + red[2] + red[3];
}

__global__ void finish2(const float* __restrict__ blockSums, float* __restrict__ out)
{
    const int lane = threadIdx.x;
    float v = (lane < 32) ? blockSums[lane] : 0.0f;
    #pragma unroll
    for (int m = 1; m < 64; m <<= 1) v += __shfl_xor(v, m, 64);
    if (lane == 0) out[0] = v * (1.0f / 8192.0f);
}

// ---------------------------------------------------------------------------
extern "C" void kernel_launch(void* const* d_in, const int* in_sizes, int n_in,
                              void* d_out, int out_size, void* d_ws, size_t ws_size,
                              hipStream_t stream) {
    const float* emb1 = (const float*)d_in[0];
    const float* emb2 = (const float*)d_in[1];
    const float* att  = (const float*)d_in[2];
    float* out = (float*)d_out;

    char* ws = (char*)d_ws;
    // X8 fp8 [8192*512]        @ 0        (4 MB)
    // inv_temp f32 [8192]      @ 4194304
    // pos f32 [4096]           @ 4227072
    // partial f32 [128*8192]   @ 4243456  (4 MB)
    // blockSums f32 [32]       @ 8437760
    unsigned short* X8 = (unsigned short*)ws;
    float* inv_temp    = (float*)(ws + 4194304);
    float* pos         = (float*)(ws + 4227072);
    float* partial     = (float*)(ws + 4243456);
    float* blockSums   = (float*)(ws + 8437760);

    static bool attr_set = false;  // host-side only; same device work every call
    if (!attr_set) {
        hipFuncSetAttribute((const void*)gram_kernel,
                            hipFuncAttributeMaxDynamicSharedMemorySize, 2 * ABUF);
        attr_set = true;
    }

    prep_kernel<<<B_ROWS, 256, 0, stream>>>(emb1, emb2, att, X8, inv_temp, pos);
    gram_kernel<<<2080, 256, 2 * ABUF, stream>>>((const unsigned char*)X8,
                                                 inv_temp, partial);
    finish1<<<TWO_B / 256, 256, 0, stream>>>(partial, pos, blockSums);
    finish2<<<1, 64, 0, stream>>>(blockSums, out);
}

// Round 12
// 130.453 us; speedup vs baseline: 1.2100x; 1.0944x over previous
//
#include <hip/hip_runtime.h>
#include <hip/hip_bf16.h>
#include <math.h>

#define B_ROWS 4096
#define D_DIM 512
#define TWO_B 8192
#define HW_N 256
#define BASE_T 0.07f
#define ALPHA_C 0.5f
#define LOG2E 1.44269504088896340736f

typedef float v4f __attribute__((ext_vector_type(4)));

__device__ __forceinline__ float fast_exp2(float x) {
#if __has_builtin(__builtin_amdgcn_exp2f)
    return __builtin_amdgcn_exp2f(x);
#else
    return exp2f(x);
#endif
}

// ---------------------------------------------------------------------------
// Kernel 1: normalize, temps, pos_sim; write X as packed fp8 e4m3 (OCP).
// ---------------------------------------------------------------------------
__global__ __launch_bounds__(256) void prep_kernel(
    const float* __restrict__ emb1, const float* __restrict__ emb2,
    const float* __restrict__ att, unsigned short* __restrict__ X8,
    float* __restrict__ inv_temp, float* __restrict__ pos)
{
    const int b = blockIdx.x;
    const int t = threadIdx.x;
    const float2 a1 = ((const float2*)(emb1 + (size_t)b * D_DIM))[t];
    const float2 a2 = ((const float2*)(emb2 + (size_t)b * D_DIM))[t];
    float av = att[(size_t)b * HW_N + t];
    float s1  = a1.x * a1.x + a1.y * a1.y;
    float s2  = a2.x * a2.x + a2.y * a2.y;
    float s12 = a1.x * a2.x + a1.y * a2.y;
    #pragma unroll
    for (int m = 1; m < 64; m <<= 1) {
        s1  += __shfl_xor(s1, m, 64);
        s2  += __shfl_xor(s2, m, 64);
        s12 += __shfl_xor(s12, m, 64);
        av  += __shfl_xor(av, m, 64);
    }
    __shared__ float red[4][4];
    const int w = t >> 6, lane = t & 63;
    if (lane == 0) { red[w][0] = s1; red[w][1] = s2; red[w][2] = s12; red[w][3] = av; }
    __syncthreads();
    const float T1  = red[0][0] + red[1][0] + red[2][0] + red[3][0];
    const float T2  = red[0][1] + red[1][1] + red[2][1] + red[3][1];
    const float T12 = red[0][2] + red[1][2] + red[2][2] + red[3][2];
    const float Ta  = red[0][3] + red[1][3] + red[2][3] + red[3][3];
    const float i1 = 1.0f / fmaxf(sqrtf(T1), 1e-12f);
    const float i2 = 1.0f / fmaxf(sqrtf(T2), 1e-12f);
    const float it = 1.0f / (BASE_T * (1.0f + ALPHA_C * (Ta * (1.0f / 256.0f))));
    const int p1 = __builtin_amdgcn_cvt_pk_fp8_f32(a1.x * i1, a1.y * i1, 0, false);
    const int p2 = __builtin_amdgcn_cvt_pk_fp8_f32(a2.x * i2, a2.y * i2, 0, false);
    X8[(size_t)b * 256 + t]            = (unsigned short)(p1 & 0xffff);
    X8[(size_t)(b + B_ROWS) * 256 + t] = (unsigned short)(p2 & 0xffff);
    if (t == 0) {
        inv_temp[b] = it * LOG2E;
        inv_temp[b + B_ROWS] = it * LOG2E;
        pos[b] = (T12 * i1 * i2) * it;       // ln units, exact fp32
    }
}

// ---------------------------------------------------------------------------
// Kernel 2: triangular Gram (rb<=cb), FP8 e4m3. R8 structure, ONE change:
// BK=128 with 32 KB static LDS -> 5 blocks/CU (vs R8's 2). 4 phases; the
// extra drains should be hidden by cross-block overlap (residency test).
// Staging: glds 8-rows x 8-chunk groups, XOR swizzle gc = chunk ^ row
// (R6's scheme, measured 0 conflicts). Fused exp row/col sums unchanged.
// ---------------------------------------------------------------------------
__device__ __forceinline__ void gload_lds16(const void* g, void* s) {
    __builtin_amdgcn_global_load_lds(
        (const __attribute__((address_space(1))) unsigned int*)g,
        (__attribute__((address_space(3))) unsigned int*)s,
        16, 0, 0);
}

__global__ __launch_bounds__(256) void gram_kernel(
    const unsigned char* __restrict__ X8,
    const float* __restrict__ inv_temp,
    float* __restrict__ partial)
{
    // 128 rows x 128 B (BK=128 fp8) each: 16 KB + 16 KB = 32 KB total
    __shared__ unsigned char smA[128 * 128];
    __shared__ unsigned char smB[128 * 128];

    // --- XCD-contiguous remap: 2080 = 8 XCDs x 260 contiguous tri-ids ---
    const int bid = (blockIdx.x & 7) * 260 + (blockIdx.x >> 3);
    int rb = (int)((129.0f - sqrtf(129.0f * 129.0f - 8.0f * (float)bid)) * 0.5f);
    rb = rb < 0 ? 0 : (rb > 63 ? 63 : rb);
    while (rb > 0 && (rb * (129 - rb)) / 2 > bid) rb--;
    while (rb < 63 && ((rb + 1) * (129 - (rb + 1))) / 2 <= bid) rb++;
    const int cb = rb + (bid - (rb * (129 - rb)) / 2);

    const int rowBase = rb * 128;
    const int colBase = cb * 128;

    const int tid  = threadIdx.x;
    const int w    = tid >> 6;
    const int lane = tid & 63;
    const int quad = lane >> 4;
    const int t    = lane & 15;
    const int wm   = w >> 1;
    const int wn   = w & 1;

    // staging roles: each glds covers 8 rows x 8 chunks(16B) = 1 KB
    const int srow   = lane >> 3;   // 0..7
    const int schunk = lane & 7;    // 0..7
    const int gc     = schunk ^ srow;   // XOR swizzle via global address

    const unsigned char* Arow0 = X8 + (size_t)rowBase * D_DIM;
    const unsigned char* Brow0 = X8 + (size_t)colBase * D_DIM;

    v4f acc[4][4];
    #pragma unroll
    for (int a = 0; a < 4; a++)
        #pragma unroll
        for (int b2 = 0; b2 < 4; b2++)
            acc[a][b2] = v4f{0.0f, 0.0f, 0.0f, 0.0f};

    for (int p = 0; p < 4; p++) {
        const int kk = p * 128;     // byte offset into each 512 B row
        #pragma unroll
        for (int j = 0; j < 4; j++) {
            const int g = w * 4 + j;            // row group 0..15 (8 rows)
            const int r = g * 8 + srow;
            gload_lds16(Arow0 + (size_t)r * D_DIM + kk + gc * 16, &smA[g * 1024]);
            gload_lds16(Brow0 + (size_t)r * D_DIM + kk + gc * 16, &smB[g * 1024]);
        }
        __syncthreads();

        #pragma unroll
        for (int s = 0; s < 4; s++) {
            // lane's 8 k-bytes: unit u = s*2 + (quad>>1), stored at u^(row&7)
            const int pu = (s * 2 + (quad >> 1)) ^ (t & 7);
            const int off = pu * 16 + (quad & 1) * 8;
            long aF[4], bF[4];
            #pragma unroll
            for (int mi = 0; mi < 4; mi++)
                aF[mi] = *(const long*)&smA[(wm * 64 + mi * 16 + t) * 128 + off];
            #pragma unroll
            for (int ni = 0; ni < 4; ni++)
                bF[ni] = *(const long*)&smB[(wn * 64 + ni * 16 + t) * 128 + off];
            #pragma unroll
            for (int mi = 0; mi < 4; mi++)
                #pragma unroll
                for (int ni = 0; ni < 4; ni++)
                    acc[mi][ni] = __builtin_amdgcn_mfma_f32_16x16x32_fp8_fp8(
                        aF[mi], bF[ni], acc[mi][ni], 0, 0, 0);
        }
        if (p < 3) __syncthreads();   // protect LDS before next overwrite
    }

    // ---- Epilogue 1: row sums (temp_i), slice 2*cb+wn ----
    v4f itv[4];
    #pragma unroll
    for (int mi = 0; mi < 4; mi++)
        itv[mi] = *(const v4f*)&inv_temp[rowBase + wm * 64 + mi * 16 + quad * 4];

    float* prow = partial + (size_t)(cb * 2 + wn) * TWO_B;
    #pragma unroll
    for (int mi = 0; mi < 4; mi++) {
        #pragma unroll
        for (int r = 0; r < 4; r++) {
            const int i = rowBase + wm * 64 + mi * 16 + quad * 4 + r;
            const float it = itv[mi][r];
            float s = 0.0f;
            #pragma unroll
            for (int ni = 0; ni < 4; ni++) {
                const int j = colBase + wn * 64 + ni * 16 + t;
                const float v = fast_exp2(acc[mi][ni][r] * it);
                s += (i == j) ? 0.0f : v;
            }
            s += __shfl_xor(s, 1, 64);
            s += __shfl_xor(s, 2, 64);
            s += __shfl_xor(s, 4, 64);
            s += __shfl_xor(s, 8, 64);
            if (t == 0) prow[i] = s;
        }
    }

    // ---- Epilogue 2 (off-diag): col sums (temp_j), slice 2*rb+wm ----
    if (rb != cb) {
        float itj[4];
        float cs[4] = {0.0f, 0.0f, 0.0f, 0.0f};
        #pragma unroll
        for (int ni = 0; ni < 4; ni++)
            itj[ni] = inv_temp[colBase + wn * 64 + ni * 16 + t];
        #pragma unroll
        for (int mi = 0; mi < 4; mi++)
            #pragma unroll
            for (int r = 0; r < 4; r++)
                #pragma unroll
                for (int ni = 0; ni < 4; ni++)
                    cs[ni] += fast_exp2(acc[mi][ni][r] * itj[ni]);
        float* pcol = partial + (size_t)(rb * 2 + wm) * TWO_B;
        #pragma unroll
        for (int ni = 0; ni < 4; ni++) {
            cs[ni] += __shfl_xor(cs[ni], 16, 64);
            cs[ni] += __shfl_xor(cs[ni], 32, 64);
            if (quad == 0) pcol[colBase + wn * 64 + ni * 16 + t] = cs[ni];
        }
    }
}

// ---------------------------------------------------------------------------
// Kernel 3a: denom = sum of 128 slices; loss_i = log(denom) - pos; block sums
// ---------------------------------------------------------------------------
__global__ __launch_bounds__(256) void finish1(
    const float* __restrict__ partial, const float* __restrict__ pos,
    float* __restrict__ blockSums)
{
    const int i = blockIdx.x * 256 + threadIdx.x;
    float d = 0.0f;
    #pragma unroll 8
    for (int s = 0; s < 128; s++) d += partial[(size_t)s * TWO_B + i];
    float li = logf(d) - pos[i & (B_ROWS - 1)];
    #pragma unroll
    for (int m = 1; m < 64; m <<= 1) li += __shfl_xor(li, m, 64);
    __shared__ float red[4];
    const int w = threadIdx.x >> 6, lane = threadIdx.x & 63;
    if (lane == 0) red[w] = li;
    __syncthreads();
    if (threadIdx.x == 0) blockSums[blockIdx.x] = red[0] + red[1] + red[2] + red[3];
}

__global__ void finish2(const float* __restrict__ blockSums, float* __restrict__ out)
{
    const int lane = threadIdx.x;
    float v = (lane < 32) ? blockSums[lane] : 0.0f;
    #pragma unroll
    for (int m = 1; m < 64; m <<= 1) v += __shfl_xor(v, m, 64);
    if (lane == 0) out[0] = v * (1.0f / 8192.0f);
}

// ---------------------------------------------------------------------------
extern "C" void kernel_launch(void* const* d_in, const int* in_sizes, int n_in,
                              void* d_out, int out_size, void* d_ws, size_t ws_size,
                              hipStream_t stream) {
    const float* emb1 = (const float*)d_in[0];
    const float* emb2 = (const float*)d_in[1];
    const float* att  = (const float*)d_in[2];
    float* out = (float*)d_out;

    char* ws = (char*)d_ws;
    // X8 fp8 [8192*512]        @ 0        (4 MB)
    // inv_temp f32 [8192]      @ 4194304
    // pos f32 [4096]           @ 4227072
    // partial f32 [128*8192]   @ 4243456  (4 MB)
    // blockSums f32 [32]       @ 8437760
    unsigned short* X8 = (unsigned short*)ws;
    float* inv_temp    = (float*)(ws + 4194304);
    float* pos         = (float*)(ws + 4227072);
    float* partial     = (float*)(ws + 4243456);
    float* blockSums   = (float*)(ws + 8437760);

    prep_kernel<<<B_ROWS, 256, 0, stream>>>(emb1, emb2, att, X8, inv_temp, pos);
    gram_kernel<<<2080, 256, 0, stream>>>((const unsigned char*)X8, inv_temp, partial);
    finish1<<<TWO_B / 256, 256, 0, stream>>>(partial, pos, blockSums);
    finish2<<<1, 64, 0, stream>>>(blockSums, out);
}